// Round 5
// baseline (1622.119 us; speedup 1.0000x reference)
//
#include <hip/hip_runtime.h>

typedef unsigned short ushort_t;
typedef __attribute__((ext_vector_type(8))) short short8;
typedef __attribute__((ext_vector_type(4))) float f32x4;

__device__ __forceinline__ ushort_t f2bf(float f) {
    union { float f; unsigned int u; } c; c.f = f;
    unsigned int r = c.u + 0x7fffu + ((c.u >> 16) & 1u);  // RNE
    return (ushort_t)(r >> 16);
}

// ---------------------------------------------------------------------------
// Kernel 0: convert W1 (256x128) and W2 (128x64) fp32 -> bf16 in MFMA
// B-fragment order. Fragment (nt,kt): lane l holds W[k][n] for
// n = nt*16 + (l&15), k = kt*32 + (l>>4)*8 + j, j=0..7 (contiguous 16B).
// ---------------------------------------------------------------------------
__global__ __launch_bounds__(256) void build_wfrags(
    const float* __restrict__ W1, const float* __restrict__ W2,
    ushort_t* __restrict__ W1f, ushort_t* __restrict__ W2f)
{
    int tid = blockIdx.x * 256 + threadIdx.x;
    if (tid < 32768) {
        int j = tid & 7, l = (tid >> 3) & 63, fi = tid >> 9; // fi = nt*8+kt
        int nt = fi >> 3, kt = fi & 7;
        int n = nt * 16 + (l & 15);
        int k = kt * 32 + (l >> 4) * 8 + j;
        W1f[tid] = f2bf(W1[k * 128 + n]);
    } else if (tid < 40960) {
        int u = tid - 32768;
        int j = u & 7, l = (u >> 3) & 63, fi = u >> 9;      // fi = nt*4+kt
        int nt = fi >> 2, kt = fi & 3;
        int n = nt * 16 + (l & 15);
        int k = kt * 32 + (l >> 4) * 8 + j;
        W2f[u] = f2bf(W2[k * 64 + n]);
    }
}

// ---------------------------------------------------------------------------
// R5 FUSED kernel: one block (8 waves) per graph, reads X from HBM ONCE.
//   Phase A: per-graph MLP logits (verified wave-MLP code from R0-R4:
//            L1 64 MFMA w/ W1f B-frags streamed from L2, wave-private LDS
//            transpose, L2 16 MFMA, quad shuffle reduce) -> logits in LDS.
//   Softmax stats over <=~260 logits (block reduce, trivial).
//   Phase B: weighted sum re-reading this graph's X rows — just touched by
//            this block, so served from L1/L2/L3, not HBM. fp32 precision
//            identical to the previous separate pool kernel.
// R4 post-mortem: R1-R3 occupancy stack was NEUTRAL (852 vs 845 µs); no
// single kernel >248 µs -> cost is spread across 4 passes; HBM floor ~190 µs
// -> the double X pass + per-kernel tails are the structural cost. This
// fuses them. LDS 63552 B -> 2 blocks/CU (16 waves/CU).
// ---------------------------------------------------------------------------
#define FW_WAVES 8
#define FUSED_CAP 1024              // max rows/graph (mean 98/195, P>512 ~ 0)
#define FUSED_LDS (16384 + 34816 + 4096 + 8192 + 64)  // 63552

__global__ __launch_bounds__(512, 4) void fused_pool(
    const float* __restrict__ X, const int* __restrict__ idx,
    const ushort_t* __restrict__ W1f, const ushort_t* __restrict__ W2f,
    const float* __restrict__ b1, const float* __restrict__ b2,
    const float* __restrict__ W3, const float* __restrict__ b3,
    float* __restrict__ out, int nrows)
{
    extern __shared__ __align__(16) char smem[];
    ushort_t* W2s      = (ushort_t*)smem;              // 16384 B (16 frags)
    ushort_t* h1base   = (ushort_t*)(smem + 16384);    // 8 waves * 4352 B
    float*    logits_s = (float*)(smem + 51200);       // 1024 * 4 B
    float*    parts    = (float*)(smem + 55296);       // 8 * 256 * 4 B
    float*    red      = (float*)(smem + 63488);       // 16 * 4 B

    const int g = blockIdx.x;
    const int t = threadIdx.x;
    const int w = t >> 6, lane = t & 63;
    const int q = lane >> 4, c16 = lane & 15;

    // segment bounds of graph g (idx sorted ascending)
    int lo = 0, hi = nrows;
    while (lo < hi) { int mid = (lo + hi) >> 1; if (idx[mid] < g) lo = mid + 1; else hi = mid; }
    const int start = lo;
    hi = nrows;
    while (lo < hi) { int mid = (lo + hi) >> 1; if (idx[mid] < g + 1) lo = mid + 1; else hi = mid; }
    const int cnt = lo - start;

    // cooperative W2 stage (16 KB, L2-hot)
    {
        const f32x4* s2 = (const f32x4*)W2f; f32x4* d2 = (f32x4*)W2s;
        for (int i = t; i < 1024; i += 512) d2[i] = s2[i];
    }
    __syncthreads();

    float bias1[8], bias2[4], w3v[4];
    #pragma unroll
    for (int nt = 0; nt < 8; ++nt) bias1[nt] = b1[nt * 16 + c16];
    #pragma unroll
    for (int nt = 0; nt < 4; ++nt) bias2[nt] = b2[nt * 16 + c16];
    #pragma unroll
    for (int nt = 0; nt < 4; ++nt) w3v[nt] = W3[nt * 16 + c16];
    const float b3v = b3[0];

    ushort_t* hw = h1base + w * (16 * 136);   // wave-private scratch

    // ---------------- Phase A: logits for this graph's rows ----------------
    const int nsub_g = (cnt + 15) >> 4;
    for (int sg = w; sg < nsub_g; sg += FW_WAVES) {
        int rowi = sg * 16 + c16;
        if (rowi >= cnt) rowi = cnt - 1;           // tail clamp (dup row, discarded)
        const float* xp = X + (size_t)(start + rowi) * 256 + q * 8;

        // Two-phase X stage: 8 dwordx4 in flight, reuse fp32 staging regs.
        short8 av[8];
        {
            f32x4 xv[8];
            #pragma unroll
            for (int kt = 0; kt < 4; ++kt) {
                xv[2 * kt]     = *(const f32x4*)(xp + kt * 32);
                xv[2 * kt + 1] = *(const f32x4*)(xp + kt * 32 + 4);
            }
            #pragma unroll
            for (int kt = 0; kt < 4; ++kt)
                #pragma unroll
                for (int j = 0; j < 4; ++j) {
                    av[kt][j]     = (short)f2bf(xv[2 * kt][j]);
                    av[kt][4 + j] = (short)f2bf(xv[2 * kt + 1][j]);
                }
            #pragma unroll
            for (int kt = 4; kt < 8; ++kt) {
                xv[2 * (kt - 4)]     = *(const f32x4*)(xp + kt * 32);
                xv[2 * (kt - 4) + 1] = *(const f32x4*)(xp + kt * 32 + 4);
            }
            #pragma unroll
            for (int kt = 4; kt < 8; ++kt)
                #pragma unroll
                for (int j = 0; j < 4; ++j) {
                    av[kt][j]     = (short)f2bf(xv[2 * (kt - 4)][j]);
                    av[kt][4 + j] = (short)f2bf(xv[2 * (kt - 4) + 1][j]);
                }
        }

        // Layer 1: [16x256] @ [256x128], B-fragments streamed from L2
        f32x4 acc[8];
        #pragma unroll
        for (int nt = 0; nt < 8; ++nt) acc[nt] = (f32x4){0.f, 0.f, 0.f, 0.f};
        #pragma unroll
        for (int kt = 0; kt < 8; ++kt) {
            #pragma unroll
            for (int nt = 0; nt < 8; ++nt) {
                short8 bf = *(const short8*)(W1f + ((nt * 8 + kt) * 64 + lane) * 8);
                acc[nt] = __builtin_amdgcn_mfma_f32_16x16x32_bf16(av[kt], bf, acc[nt], 0, 0, 0);
            }
        }

        // bias+relu, C-layout -> row-major bf16 in wave-private LDS
        #pragma unroll
        for (int nt = 0; nt < 8; ++nt)
            #pragma unroll
            for (int reg = 0; reg < 4; ++reg)
                hw[(q * 4 + reg) * 136 + nt * 16 + c16] =
                    f2bf(fmaxf(acc[nt][reg] + bias1[nt], 0.f));

        // Layer 2: [16x128] @ [128x64]  (same-wave ds ordering, no barrier)
        f32x4 acc2[4];
        #pragma unroll
        for (int nt = 0; nt < 4; ++nt) acc2[nt] = (f32x4){0.f, 0.f, 0.f, 0.f};
        #pragma unroll
        for (int kt = 0; kt < 4; ++kt) {
            short8 a = *(const short8*)(hw + c16 * 136 + kt * 32 + q * 8);
            #pragma unroll
            for (int nt = 0; nt < 4; ++nt) {
                short8 bf = *(const short8*)(W2s + ((nt * 4 + kt) * 64 + lane) * 8);
                acc2[nt] = __builtin_amdgcn_mfma_f32_16x16x32_bf16(a, bf, acc2[nt], 0, 0, 0);
            }
        }

        // Layer 3: relu, dot with W3, reduce over 16 lanes per quad
        float p[4];
        #pragma unroll
        for (int reg = 0; reg < 4; ++reg) {
            float v = 0.f;
            #pragma unroll
            for (int nt = 0; nt < 4; ++nt)
                v += fmaxf(acc2[nt][reg] + bias2[nt], 0.f) * w3v[nt];
            p[reg] = v;
        }
        #pragma unroll
        for (int msk = 1; msk < 16; msk <<= 1)
            #pragma unroll
            for (int reg = 0; reg < 4; ++reg)
                p[reg] += __shfl_xor(p[reg], msk);
        if (c16 == 0) {
            #pragma unroll
            for (int reg = 0; reg < 4; ++reg) {
                int r = sg * 16 + q * 4 + reg;
                if (r < cnt) logits_s[r] = p[reg] + b3v;
            }
        }
    }
    __syncthreads();

    // ---------------- softmax stats over cnt logits ----------------
    float m = -3.0e38f;
    for (int i = t; i < cnt; i += 512) m = fmaxf(m, logits_s[i]);
    #pragma unroll
    for (int o = 32; o; o >>= 1) m = fmaxf(m, __shfl_xor(m, o));
    if (lane == 0) red[w] = m;
    __syncthreads();
    m = red[0];
    #pragma unroll
    for (int i = 1; i < 8; ++i) m = fmaxf(m, red[i]);

    float ssum = 0.f;
    for (int i = t; i < cnt; i += 512) ssum += __expf(logits_s[i] - m);
    #pragma unroll
    for (int o = 32; o; o >>= 1) ssum += __shfl_xor(ssum, o);
    if (lane == 0) red[8 + w] = ssum;
    __syncthreads();
    ssum = 0.f;
    #pragma unroll
    for (int i = 0; i < 8; ++i) ssum += red[8 + i];
    const float inv = (cnt > 0) ? 1.f / ssum : 0.f;

    // ---------------- Phase B: weighted sum (rows L1/L2/L3-hot) ----------------
    // wave w owns rows {w, w+8, ...}; lane owns dims lane*4..lane*4+3
    f32x4 acc = {0.f, 0.f, 0.f, 0.f};
    const float* xb = X + (size_t)start * 256 + lane * 4;
    int r = w;
    for (; r + 24 < cnt; r += 32) {
        float a0 = __expf(logits_s[r] - m);
        float a1 = __expf(logits_s[r + 8] - m);
        float a2 = __expf(logits_s[r + 16] - m);
        float a3 = __expf(logits_s[r + 24] - m);
        f32x4 x0 = *(const f32x4*)(xb + (size_t)(r) * 256);
        f32x4 x1 = *(const f32x4*)(xb + (size_t)(r + 8) * 256);
        f32x4 x2 = *(const f32x4*)(xb + (size_t)(r + 16) * 256);
        f32x4 x3 = *(const f32x4*)(xb + (size_t)(r + 24) * 256);
        acc += a0 * x0;
        acc += a1 * x1;
        acc += a2 * x2;
        acc += a3 * x3;
    }
    for (; r < cnt; r += 8) {
        float a = __expf(logits_s[r] - m);
        f32x4 xv = *(const f32x4*)(xb + (size_t)r * 256);
        acc += a * xv;
    }
    #pragma unroll
    for (int j = 0; j < 4; ++j) parts[w * 256 + lane * 4 + j] = acc[j] * inv;
    __syncthreads();
    if (t < 256) {
        float v = 0.f;
        #pragma unroll
        for (int i = 0; i < 8; ++i) v += parts[i * 256 + t];
        out[(size_t)g * 256 + t] = v;
    }
}

// ---------------------------------------------------------------------------

extern "C" void kernel_launch(void* const* d_in, const int* in_sizes, int n_in,
                              void* d_out, int out_size, void* d_ws, size_t ws_size,
                              hipStream_t stream) {
    const float* Xn  = (const float*)d_in[0];
    const float* Xe  = (const float*)d_in[1];
    const int* idxn  = (const int*)d_in[2];
    const int* idxe  = (const int*)d_in[3];
    const float* Wn1 = (const float*)d_in[4];
    const float* bn1 = (const float*)d_in[5];
    const float* Wn2 = (const float*)d_in[6];
    const float* bn2 = (const float*)d_in[7];
    const float* Wn3 = (const float*)d_in[8];
    const float* bn3 = (const float*)d_in[9];
    const float* We1 = (const float*)d_in[10];
    const float* be1 = (const float*)d_in[11];
    const float* We2 = (const float*)d_in[12];
    const float* be2 = (const float*)d_in[13];
    const float* We3 = (const float*)d_in[14];
    const float* be3 = (const float*)d_in[15];
    float* out = (float*)d_out;

    char* ws = (char*)d_ws;
    ushort_t* W1f_n = (ushort_t*)(ws + 0);        // 65536 B
    ushort_t* W2f_n = (ushort_t*)(ws + 65536);    // 16384 B
    ushort_t* W1f_e = (ushort_t*)(ws + 81920);    // 65536 B
    ushort_t* W2f_e = (ushort_t*)(ws + 147456);   // 16384 B

    (void)hipFuncSetAttribute((const void*)fused_pool,
                              hipFuncAttributeMaxDynamicSharedMemorySize,
                              FUSED_LDS);

    build_wfrags<<<160, 256, 0, stream>>>(Wn1, Wn2, W1f_n, W2f_n);
    build_wfrags<<<160, 256, 0, stream>>>(We1, We2, W1f_e, W2f_e);

    fused_pool<<<2048, 512, FUSED_LDS, stream>>>(
        Xn, idxn, W1f_n, W2f_n, bn1, bn2, Wn3, bn3, out, 200000);
    fused_pool<<<2048, 512, FUSED_LDS, stream>>>(
        Xe, idxe, W1f_e, W2f_e, be1, be2, We3, be3,
        out + (size_t)2048 * 256, 400000);
}

// Round 7
// 869.557 us; speedup vs baseline: 1.8655x; 1.8655x over previous
//
#include <hip/hip_runtime.h>

typedef unsigned short ushort_t;
typedef __attribute__((ext_vector_type(8))) short short8;
typedef __attribute__((ext_vector_type(4))) float f32x4;

__device__ __forceinline__ ushort_t f2bf(float f) {
    union { float f; unsigned int u; } c; c.f = f;
    unsigned int r = c.u + 0x7fffu + ((c.u >> 16) & 1u);  // RNE
    return (ushort_t)(r >> 16);
}

// ---------------------------------------------------------------------------
// Kernel 0: convert W1 (256x128) and W2 (128x64) fp32 -> bf16 in MFMA
// B-fragment order. Fragment (nt,kt): lane l holds W[k][n] for
// n = nt*16 + (l&15), k = kt*32 + (l>>4)*8 + j, j=0..7 (contiguous 16B).
// ---------------------------------------------------------------------------
__global__ __launch_bounds__(256) void build_wfrags(
    const float* __restrict__ W1, const float* __restrict__ W2,
    ushort_t* __restrict__ W1f, ushort_t* __restrict__ W2f)
{
    int tid = blockIdx.x * 256 + threadIdx.x;
    if (tid < 32768) {
        int j = tid & 7, l = (tid >> 3) & 63, fi = tid >> 9; // fi = nt*8+kt
        int nt = fi >> 3, kt = fi & 7;
        int n = nt * 16 + (l & 15);
        int k = kt * 32 + (l >> 4) * 8 + j;
        W1f[tid] = f2bf(W1[k * 128 + n]);
    } else if (tid < 40960) {
        int u = tid - 32768;
        int j = u & 7, l = (u >> 3) & 63, fi = u >> 9;      // fi = nt*4+kt
        int nt = fi >> 2, kt = fi & 3;
        int n = nt * 16 + (l & 15);
        int k = kt * 32 + (l >> 4) * 8 + j;
        W2f[u] = f2bf(W2[k * 64 + n]);
    }
}

// ---------------------------------------------------------------------------
// Kernel 1: per-row MLP logits.
// R5 POST-MORTEM (counters): fused variant showed VGPR_Count=64 +
// WRITE_SIZE=891 MB/dispatch (expected 2 MB) -> the old 16-reg persistent
// X-staging body EXCEEDS the unified VGPR+AGPR 128-reg cap imposed by
// __launch_bounds__(512,4) (acc[8]+acc2[4] accumulators share the file on
// gfx950!) and spilled ~850 B/thread to scratch through HBM.
// R6 FIX: STREAMING Layer-1 — per kt: load 32 B of X, convert, feed 8 MFMAs.
// Live set ~60 arch + 48 accum <= 128 -> no spills AND real 2 blocks/CU
// (LDS 51200 B x2 = 100 KB < 160 KB). Unrolled loop lets the scheduler hoist
// kt+1 loads over kt MFMAs; 4 waves/SIMD TLP hides the L2-hit W1f stream.
// R7: HOLD byte-identical (R6 never ran — GPU timeout). Pre-committed read:
// WRITE_SIZE ~ logits size => spill fixed; WRITE_SIZE >> 10 MB => cap must go.
// W2 (16 KB, reused by all subtiles) stays staged in LDS.
// ---------------------------------------------------------------------------
#define MLP_WAVES 8
#define MLP_TPW 1
#define MLP_LDS_BYTES (16384 + MLP_WAVES * 16 * 136 * 2)  // 51200

__global__ __launch_bounds__(512, 4) void mlp_logits(
    const float* __restrict__ X, const ushort_t* __restrict__ W1f,
    const ushort_t* __restrict__ W2f, const float* __restrict__ b1,
    const float* __restrict__ b2, const float* __restrict__ W3,
    const float* __restrict__ b3, float* __restrict__ logits, int nsub)
{
    extern __shared__ __align__(16) char smem[];
    ushort_t* W2s    = (ushort_t*)smem;             // 16384 B (16 frags)
    ushort_t* h1base = (ushort_t*)(smem + 16384);   // 8 waves * 4352 B

    const int t = threadIdx.x;
    const int w = t >> 6, lane = t & 63;
    const int q = lane >> 4, c16 = lane & 15;

    // cooperative W2 stage (L2-hot, once per block)
    {
        const f32x4* s2 = (const f32x4*)W2f; f32x4* d2 = (f32x4*)smem;
        for (int i = t; i < 1024; i += 512) d2[i] = s2[i];
    }
    __syncthreads();

    float bias1[8], bias2[4], w3v[4];
    #pragma unroll
    for (int nt = 0; nt < 8; ++nt) bias1[nt] = b1[nt * 16 + c16];
    #pragma unroll
    for (int nt = 0; nt < 4; ++nt) bias2[nt] = b2[nt * 16 + c16];
    #pragma unroll
    for (int nt = 0; nt < 4; ++nt) w3v[nt] = W3[nt * 16 + c16];
    const float b3v = b3[0];

    ushort_t* hw = h1base + w * (16 * 136);   // wave-private scratch

    for (int sub = 0; sub < MLP_TPW; ++sub) {
        const int s = (blockIdx.x * MLP_WAVES + w) * MLP_TPW + sub;
        if (s >= nsub) break;
        const float* xp = X + (size_t)(s * 16 + c16) * 256 + q * 8;

        // Layer 1: [16x256] @ [256x128] — STREAMING: per kt, load 32 B of X,
        // convert to one A-fragment, feed 8 MFMAs (B-frags from L2).
        f32x4 acc[8];
        #pragma unroll
        for (int nt = 0; nt < 8; ++nt) acc[nt] = (f32x4){0.f, 0.f, 0.f, 0.f};
        #pragma unroll
        for (int kt = 0; kt < 8; ++kt) {
            f32x4 x0 = *(const f32x4*)(xp + kt * 32);
            f32x4 x1 = *(const f32x4*)(xp + kt * 32 + 4);
            short8 a;
            #pragma unroll
            for (int j = 0; j < 4; ++j) {
                a[j]     = (short)f2bf(x0[j]);
                a[4 + j] = (short)f2bf(x1[j]);
            }
            #pragma unroll
            for (int nt = 0; nt < 8; ++nt) {
                short8 bf = *(const short8*)(W1f + ((nt * 8 + kt) * 64 + lane) * 8);
                acc[nt] = __builtin_amdgcn_mfma_f32_16x16x32_bf16(a, bf, acc[nt], 0, 0, 0);
            }
        }

        // bias+relu, C-layout -> row-major bf16 in wave-private LDS
        #pragma unroll
        for (int nt = 0; nt < 8; ++nt)
            #pragma unroll
            for (int reg = 0; reg < 4; ++reg)
                hw[(q * 4 + reg) * 136 + nt * 16 + c16] =
                    f2bf(fmaxf(acc[nt][reg] + bias1[nt], 0.f));

        // Layer 2: [16x128] @ [128x64]  (same-wave ds_write->ds_read, no barrier)
        f32x4 acc2[4];
        #pragma unroll
        for (int nt = 0; nt < 4; ++nt) acc2[nt] = (f32x4){0.f, 0.f, 0.f, 0.f};
        #pragma unroll
        for (int kt = 0; kt < 4; ++kt) {
            short8 a = *(const short8*)(hw + c16 * 136 + kt * 32 + q * 8);
            #pragma unroll
            for (int nt = 0; nt < 4; ++nt) {
                short8 bf = *(const short8*)(W2s + ((nt * 4 + kt) * 64 + lane) * 8);
                acc2[nt] = __builtin_amdgcn_mfma_f32_16x16x32_bf16(a, bf, acc2[nt], 0, 0, 0);
            }
        }

        // Layer 3: relu, dot with W3, reduce over 16 lanes per quad
        float p[4];
        #pragma unroll
        for (int reg = 0; reg < 4; ++reg) {
            float v = 0.f;
            #pragma unroll
            for (int nt = 0; nt < 4; ++nt)
                v += fmaxf(acc2[nt][reg] + bias2[nt], 0.f) * w3v[nt];
            p[reg] = v;
        }
        #pragma unroll
        for (int msk = 1; msk < 16; msk <<= 1)
            #pragma unroll
            for (int reg = 0; reg < 4; ++reg)
                p[reg] += __shfl_xor(p[reg], msk);
        if (c16 == 0) {
            #pragma unroll
            for (int reg = 0; reg < 4; ++reg)
                logits[s * 16 + q * 4 + reg] = p[reg] + b3v;
        }
    }
}

// ---------------------------------------------------------------------------
// Kernel 2: per-graph softmax + weighted pooling. One block (4 waves) per
// graph. Lane owns 4 dims (float4 loads, 16 B/lane); waves stride rows by 4;
// unroll-4 keeps 64 B/lane in flight. inv multiply deferred to epilogue.
// (Unchanged from the verified R4 version.)
// ---------------------------------------------------------------------------
__global__ __launch_bounds__(256) void pool(
    const float* __restrict__ X, const int* __restrict__ idx,
    const float* __restrict__ logits, float* __restrict__ out, int nrows)
{
    const int g = blockIdx.x;
    const int t = threadIdx.x;
    const int w = t >> 6, lane = t & 63;

    int lo = 0, hi = nrows;
    while (lo < hi) { int mid = (lo + hi) >> 1; if (idx[mid] < g) lo = mid + 1; else hi = mid; }
    const int start = lo;
    hi = nrows;
    while (lo < hi) { int mid = (lo + hi) >> 1; if (idx[mid] < g + 1) lo = mid + 1; else hi = mid; }
    const int cnt = lo - start;

    __shared__ float red[8];
    __shared__ float parts[4][256];

    const float* lg = logits + start;

    // segment max
    float m = -3.0e38f;
    for (int i = t; i < cnt; i += 256) m = fmaxf(m, lg[i]);
    #pragma unroll
    for (int o = 32; o; o >>= 1) m = fmaxf(m, __shfl_xor(m, o));
    if (lane == 0) red[w] = m;
    __syncthreads();
    m = fmaxf(fmaxf(red[0], red[1]), fmaxf(red[2], red[3]));

    // segment exp-sum
    float ssum = 0.f;
    for (int i = t; i < cnt; i += 256) ssum += __expf(lg[i] - m);
    #pragma unroll
    for (int o = 32; o; o >>= 1) ssum += __shfl_xor(ssum, o);
    if (lane == 0) red[4 + w] = ssum;
    __syncthreads();
    ssum = red[4] + red[5] + red[6] + red[7];
    const float inv = (cnt > 0) ? 1.f / ssum : 0.f;

    // weighted accumulation: wave w rows {w, w+4, ...}, lane dims lane*4..+3
    f32x4 acc = {0.f, 0.f, 0.f, 0.f};
    const float* xb = X + (size_t)start * 256 + lane * 4;
    int r = w;
    for (; r + 12 < cnt; r += 16) {
        float a0 = __expf(lg[r] - m);
        float a1 = __expf(lg[r + 4] - m);
        float a2 = __expf(lg[r + 8] - m);
        float a3 = __expf(lg[r + 12] - m);
        f32x4 x0 = *(const f32x4*)(xb + (size_t)(r) * 256);
        f32x4 x1 = *(const f32x4*)(xb + (size_t)(r + 4) * 256);
        f32x4 x2 = *(const f32x4*)(xb + (size_t)(r + 8) * 256);
        f32x4 x3 = *(const f32x4*)(xb + (size_t)(r + 12) * 256);
        acc += a0 * x0;
        acc += a1 * x1;
        acc += a2 * x2;
        acc += a3 * x3;
    }
    for (; r < cnt; r += 4) {
        float a = __expf(lg[r] - m);
        f32x4 xv = *(const f32x4*)(xb + (size_t)r * 256);
        acc += a * xv;
    }
    #pragma unroll
    for (int j = 0; j < 4; ++j) parts[w][lane * 4 + j] = acc[j] * inv;
    __syncthreads();
    out[(size_t)g * 256 + t] = parts[0][t] + parts[1][t] + parts[2][t] + parts[3][t];
}

// ---------------------------------------------------------------------------

extern "C" void kernel_launch(void* const* d_in, const int* in_sizes, int n_in,
                              void* d_out, int out_size, void* d_ws, size_t ws_size,
                              hipStream_t stream) {
    const float* Xn  = (const float*)d_in[0];
    const float* Xe  = (const float*)d_in[1];
    const int* idxn  = (const int*)d_in[2];
    const int* idxe  = (const int*)d_in[3];
    const float* Wn1 = (const float*)d_in[4];
    const float* bn1 = (const float*)d_in[5];
    const float* Wn2 = (const float*)d_in[6];
    const float* bn2 = (const float*)d_in[7];
    const float* Wn3 = (const float*)d_in[8];
    const float* bn3 = (const float*)d_in[9];
    const float* We1 = (const float*)d_in[10];
    const float* be1 = (const float*)d_in[11];
    const float* We2 = (const float*)d_in[12];
    const float* be2 = (const float*)d_in[13];
    const float* We3 = (const float*)d_in[14];
    const float* be3 = (const float*)d_in[15];
    float* out = (float*)d_out;

    char* ws = (char*)d_ws;
    ushort_t* W1f_n = (ushort_t*)(ws + 0);        // 65536 B
    ushort_t* W2f_n = (ushort_t*)(ws + 65536);    // 16384 B
    ushort_t* W1f_e = (ushort_t*)(ws + 81920);    // 65536 B
    ushort_t* W2f_e = (ushort_t*)(ws + 147456);   // 16384 B
    float* log_n = (float*)(ws + 163840);         // 200000*4 B
    float* log_e = (float*)(ws + 963840);         // 400000*4 B

    (void)hipFuncSetAttribute((const void*)mlp_logits,
                              hipFuncAttributeMaxDynamicSharedMemorySize,
                              MLP_LDS_BYTES);

    build_wfrags<<<160, 256, 0, stream>>>(Wn1, Wn2, W1f_n, W2f_n);
    build_wfrags<<<160, 256, 0, stream>>>(We1, We2, W1f_e, W2f_e);

    // nodes fully, then pool while X_n (204.8 MB < 256 MiB L3) is cache-hot
    const int nsub_n = 200000 / 16, nsub_e = 400000 / 16;
    const int gpb = MLP_WAVES * MLP_TPW;  // subtiles per block
    mlp_logits<<<(nsub_n + gpb - 1) / gpb, 512, MLP_LDS_BYTES, stream>>>(
        Xn, W1f_n, W2f_n, bn1, bn2, Wn3, bn3, log_n, nsub_n);
    pool<<<2048, 256, 0, stream>>>(Xn, idxn, log_n, out, 200000);

    mlp_logits<<<(nsub_e + gpb - 1) / gpb, 512, MLP_LDS_BYTES, stream>>>(
        Xe, W1f_e, W2f_e, be1, be2, We3, be3, log_e, nsub_e);
    pool<<<2048, 256, 0, stream>>>(Xe, idxe, log_e, out + (size_t)2048 * 256, 400000);
}

// Round 8
// 863.694 us; speedup vs baseline: 1.8781x; 1.0068x over previous
//
#include <hip/hip_runtime.h>

typedef unsigned short ushort_t;
typedef __attribute__((ext_vector_type(8))) short short8;
typedef __attribute__((ext_vector_type(4))) float f32x4;

__device__ __forceinline__ ushort_t f2bf(float f) {
    union { float f; unsigned int u; } c; c.f = f;
    unsigned int r = c.u + 0x7fffu + ((c.u >> 16) & 1u);  // RNE
    return (ushort_t)(r >> 16);
}

// ---------------------------------------------------------------------------
// Kernel 0: convert W1 (256x128) and W2 (128x64) fp32 -> bf16 in MFMA
// B-fragment order. Fragment (nt,kt): lane l holds W[k][n] for
// n = nt*16 + (l&15), k = kt*32 + (l>>4)*8 + j, j=0..7 (contiguous 16B).
// ---------------------------------------------------------------------------
__global__ __launch_bounds__(256) void build_wfrags(
    const float* __restrict__ W1, const float* __restrict__ W2,
    ushort_t* __restrict__ W1f, ushort_t* __restrict__ W2f)
{
    int tid = blockIdx.x * 256 + threadIdx.x;
    if (tid < 32768) {
        int j = tid & 7, l = (tid >> 3) & 63, fi = tid >> 9; // fi = nt*8+kt
        int nt = fi >> 3, kt = fi & 7;
        int n = nt * 16 + (l & 15);
        int k = kt * 32 + (l >> 4) * 8 + j;
        W1f[tid] = f2bf(W1[k * 128 + n]);
    } else if (tid < 40960) {
        int u = tid - 32768;
        int j = u & 7, l = (u >> 3) & 63, fi = u >> 9;      // fi = nt*4+kt
        int nt = fi >> 2, kt = fi & 3;
        int n = nt * 16 + (l & 15);
        int k = kt * 32 + (l >> 4) * 8 + j;
        W2f[u] = f2bf(W2[k * 64 + n]);
    }
}

// ---------------------------------------------------------------------------
// Kernel 1 (R8): MERGED per-row MLP logits for nodes AND edges in ONE
// dispatch. Motivation: R4/R7 counters never show our kernels (all < the
// harness's 250 µs fillBuffer wall) -> zero attribution for 3 rounds of
// neutral MLP fixes (845/852/870 µs). Merging (a) surfaces one ~2x-longer
// dispatch in top-5 WITH MfmaUtil/Occupancy/WRITE_SIZE (spill check on the
// R6 streaming body: ~2.4 MB clean vs >>10 MB spilling), (b) amortizes the
// ramp-down tail across n+e and removes one launch gap.
// Wave-uniform select: global subtile id s < nsub_n -> nodes, else edges.
// Both W2 frag sets staged in LDS (32 KB) + 34 KB h1 scratch = 67.6 KB
// -> still 2 blocks/CU. Compute body byte-identical to verified R7 code.
// ---------------------------------------------------------------------------
#define MLP_WAVES 8
#define MLP_LDS_BYTES (32768 + MLP_WAVES * 16 * 136 * 2)  // 67584

__global__ __launch_bounds__(512, 4) void mlp_logits_both(
    const float* __restrict__ Xn, const float* __restrict__ Xe,
    const ushort_t* __restrict__ W1f_n, const ushort_t* __restrict__ W2f_n,
    const ushort_t* __restrict__ W1f_e, const ushort_t* __restrict__ W2f_e,
    const float* __restrict__ bn1, const float* __restrict__ bn2,
    const float* __restrict__ Wn3, const float* __restrict__ bn3,
    const float* __restrict__ be1, const float* __restrict__ be2,
    const float* __restrict__ We3, const float* __restrict__ be3,
    float* __restrict__ log_n, float* __restrict__ log_e,
    int nsub_n, int nsub_e)
{
    extern __shared__ __align__(16) char smem[];
    ushort_t* h1base = (ushort_t*)(smem + 32768);   // 8 waves * 4352 B

    const int t = threadIdx.x;
    const int w = t >> 6, lane = t & 63;
    const int q = lane >> 4, c16 = lane & 15;

    // cooperative stage of BOTH W2 fragment sets (L2-hot, once per block)
    {
        const f32x4* sn = (const f32x4*)W2f_n; f32x4* dn = (f32x4*)smem;
        for (int i = t; i < 1024; i += 512) dn[i] = sn[i];
        const f32x4* se = (const f32x4*)W2f_e; f32x4* de = (f32x4*)(smem + 16384);
        for (int i = t; i < 1024; i += 512) de[i] = se[i];
    }
    __syncthreads();

    // wave-uniform node/edge select
    const int s_glob = blockIdx.x * MLP_WAVES + w;
    if (s_glob >= nsub_n + nsub_e) return;   // no barriers below: safe exit
    const bool is_e = (s_glob >= nsub_n);
    const int s = is_e ? (s_glob - nsub_n) : s_glob;

    const float*    X      = is_e ? Xe : Xn;
    const ushort_t* W1f    = is_e ? W1f_e : W1f_n;
    const ushort_t* W2s    = (ushort_t*)(is_e ? (smem + 16384) : smem);
    const float*    b1     = is_e ? be1 : bn1;
    const float*    b2     = is_e ? be2 : bn2;
    const float*    W3     = is_e ? We3 : Wn3;
    const float*    b3     = is_e ? be3 : bn3;
    float*          logits = is_e ? log_e : log_n;

    float bias1[8], bias2[4], w3v[4];
    #pragma unroll
    for (int nt = 0; nt < 8; ++nt) bias1[nt] = b1[nt * 16 + c16];
    #pragma unroll
    for (int nt = 0; nt < 4; ++nt) bias2[nt] = b2[nt * 16 + c16];
    #pragma unroll
    for (int nt = 0; nt < 4; ++nt) w3v[nt] = W3[nt * 16 + c16];
    const float b3v = b3[0];

    ushort_t* hw = h1base + w * (16 * 136);   // wave-private scratch

    const float* xp = X + (size_t)(s * 16 + c16) * 256 + q * 8;

    // Layer 1: [16x256] @ [256x128] — STREAMING: per kt, load 32 B of X,
    // convert to one A-fragment, feed 8 MFMAs (B-frags from L2).
    f32x4 acc[8];
    #pragma unroll
    for (int nt = 0; nt < 8; ++nt) acc[nt] = (f32x4){0.f, 0.f, 0.f, 0.f};
    #pragma unroll
    for (int kt = 0; kt < 8; ++kt) {
        f32x4 x0 = *(const f32x4*)(xp + kt * 32);
        f32x4 x1 = *(const f32x4*)(xp + kt * 32 + 4);
        short8 a;
        #pragma unroll
        for (int j = 0; j < 4; ++j) {
            a[j]     = (short)f2bf(x0[j]);
            a[4 + j] = (short)f2bf(x1[j]);
        }
        #pragma unroll
        for (int nt = 0; nt < 8; ++nt) {
            short8 bf = *(const short8*)(W1f + ((nt * 8 + kt) * 64 + lane) * 8);
            acc[nt] = __builtin_amdgcn_mfma_f32_16x16x32_bf16(a, bf, acc[nt], 0, 0, 0);
        }
    }

    // bias+relu, C-layout -> row-major bf16 in wave-private LDS
    #pragma unroll
    for (int nt = 0; nt < 8; ++nt)
        #pragma unroll
        for (int reg = 0; reg < 4; ++reg)
            hw[(q * 4 + reg) * 136 + nt * 16 + c16] =
                f2bf(fmaxf(acc[nt][reg] + bias1[nt], 0.f));

    // Layer 2: [16x128] @ [128x64]  (same-wave ds_write->ds_read, no barrier)
    f32x4 acc2[4];
    #pragma unroll
    for (int nt = 0; nt < 4; ++nt) acc2[nt] = (f32x4){0.f, 0.f, 0.f, 0.f};
    #pragma unroll
    for (int kt = 0; kt < 4; ++kt) {
        short8 a = *(const short8*)(hw + c16 * 136 + kt * 32 + q * 8);
        #pragma unroll
        for (int nt = 0; nt < 4; ++nt) {
            short8 bf = *(const short8*)(W2s + ((nt * 4 + kt) * 64 + lane) * 8);
            acc2[nt] = __builtin_amdgcn_mfma_f32_16x16x32_bf16(a, bf, acc2[nt], 0, 0, 0);
        }
    }

    // Layer 3: relu, dot with W3, reduce over 16 lanes per quad
    float p[4];
    #pragma unroll
    for (int reg = 0; reg < 4; ++reg) {
        float v = 0.f;
        #pragma unroll
        for (int nt = 0; nt < 4; ++nt)
            v += fmaxf(acc2[nt][reg] + bias2[nt], 0.f) * w3v[nt];
        p[reg] = v;
    }
    #pragma unroll
    for (int msk = 1; msk < 16; msk <<= 1)
        #pragma unroll
        for (int reg = 0; reg < 4; ++reg)
            p[reg] += __shfl_xor(p[reg], msk);
    if (c16 == 0) {
        #pragma unroll
        for (int reg = 0; reg < 4; ++reg)
            logits[s * 16 + q * 4 + reg] = p[reg] + b3v;
    }
}

// ---------------------------------------------------------------------------
// Kernel 2 (R8): MERGED per-graph softmax + weighted pooling, nodes+edges in
// one 4096-block dispatch (block-uniform select; out rows 0..2047 = nodes,
// 2048..4095 = edges). Body identical to the verified R4 pool.
// ---------------------------------------------------------------------------
__global__ __launch_bounds__(256) void pool_both(
    const float* __restrict__ Xn, const float* __restrict__ Xe,
    const int* __restrict__ idxn, const int* __restrict__ idxe,
    const float* __restrict__ log_n, const float* __restrict__ log_e,
    float* __restrict__ out)
{
    const int gb = blockIdx.x;
    const bool is_e = (gb >= 2048);
    const int g = is_e ? gb - 2048 : gb;
    const float* X      = is_e ? Xe : Xn;
    const int*   idx    = is_e ? idxe : idxn;
    const float* logits = is_e ? log_e : log_n;
    const int    nrows  = is_e ? 400000 : 200000;

    const int t = threadIdx.x;
    const int w = t >> 6, lane = t & 63;

    int lo = 0, hi = nrows;
    while (lo < hi) { int mid = (lo + hi) >> 1; if (idx[mid] < g) lo = mid + 1; else hi = mid; }
    const int start = lo;
    hi = nrows;
    while (lo < hi) { int mid = (lo + hi) >> 1; if (idx[mid] < g + 1) lo = mid + 1; else hi = mid; }
    const int cnt = lo - start;

    __shared__ float red[8];
    __shared__ float parts[4][256];

    const float* lg = logits + start;

    // segment max
    float m = -3.0e38f;
    for (int i = t; i < cnt; i += 256) m = fmaxf(m, lg[i]);
    #pragma unroll
    for (int o = 32; o; o >>= 1) m = fmaxf(m, __shfl_xor(m, o));
    if (lane == 0) red[w] = m;
    __syncthreads();
    m = fmaxf(fmaxf(red[0], red[1]), fmaxf(red[2], red[3]));

    // segment exp-sum
    float ssum = 0.f;
    for (int i = t; i < cnt; i += 256) ssum += __expf(lg[i] - m);
    #pragma unroll
    for (int o = 32; o; o >>= 1) ssum += __shfl_xor(ssum, o);
    if (lane == 0) red[4 + w] = ssum;
    __syncthreads();
    ssum = red[4] + red[5] + red[6] + red[7];
    const float inv = (cnt > 0) ? 1.f / ssum : 0.f;

    // weighted accumulation: wave w rows {w, w+4, ...}, lane dims lane*4..+3
    f32x4 acc = {0.f, 0.f, 0.f, 0.f};
    const float* xb = X + (size_t)start * 256 + lane * 4;
    int r = w;
    for (; r + 12 < cnt; r += 16) {
        float a0 = __expf(lg[r] - m);
        float a1 = __expf(lg[r + 4] - m);
        float a2 = __expf(lg[r + 8] - m);
        float a3 = __expf(lg[r + 12] - m);
        f32x4 x0 = *(const f32x4*)(xb + (size_t)(r) * 256);
        f32x4 x1 = *(const f32x4*)(xb + (size_t)(r + 4) * 256);
        f32x4 x2 = *(const f32x4*)(xb + (size_t)(r + 8) * 256);
        f32x4 x3 = *(const f32x4*)(xb + (size_t)(r + 12) * 256);
        acc += a0 * x0;
        acc += a1 * x1;
        acc += a2 * x2;
        acc += a3 * x3;
    }
    for (; r < cnt; r += 4) {
        float a = __expf(lg[r] - m);
        f32x4 xv = *(const f32x4*)(xb + (size_t)r * 256);
        acc += a * xv;
    }
    #pragma unroll
    for (int j = 0; j < 4; ++j) parts[w][lane * 4 + j] = acc[j] * inv;
    __syncthreads();
    out[(size_t)gb * 256 + t] = parts[0][t] + parts[1][t] + parts[2][t] + parts[3][t];
}

// ---------------------------------------------------------------------------

extern "C" void kernel_launch(void* const* d_in, const int* in_sizes, int n_in,
                              void* d_out, int out_size, void* d_ws, size_t ws_size,
                              hipStream_t stream) {
    const float* Xn  = (const float*)d_in[0];
    const float* Xe  = (const float*)d_in[1];
    const int* idxn  = (const int*)d_in[2];
    const int* idxe  = (const int*)d_in[3];
    const float* Wn1 = (const float*)d_in[4];
    const float* bn1 = (const float*)d_in[5];
    const float* Wn2 = (const float*)d_in[6];
    const float* bn2 = (const float*)d_in[7];
    const float* Wn3 = (const float*)d_in[8];
    const float* bn3 = (const float*)d_in[9];
    const float* We1 = (const float*)d_in[10];
    const float* be1 = (const float*)d_in[11];
    const float* We2 = (const float*)d_in[12];
    const float* be2 = (const float*)d_in[13];
    const float* We3 = (const float*)d_in[14];
    const float* be3 = (const float*)d_in[15];
    float* out = (float*)d_out;

    char* ws = (char*)d_ws;
    ushort_t* W1f_n = (ushort_t*)(ws + 0);        // 65536 B
    ushort_t* W2f_n = (ushort_t*)(ws + 65536);    // 16384 B
    ushort_t* W1f_e = (ushort_t*)(ws + 81920);    // 65536 B
    ushort_t* W2f_e = (ushort_t*)(ws + 147456);   // 16384 B
    float* log_n = (float*)(ws + 163840);         // 200000*4 B
    float* log_e = (float*)(ws + 963840);         // 400000*4 B

    (void)hipFuncSetAttribute((const void*)mlp_logits_both,
                              hipFuncAttributeMaxDynamicSharedMemorySize,
                              MLP_LDS_BYTES);

    build_wfrags<<<160, 256, 0, stream>>>(Wn1, Wn2, W1f_n, W2f_n);
    build_wfrags<<<160, 256, 0, stream>>>(We1, We2, W1f_e, W2f_e);

    const int nsub_n = 200000 / 16, nsub_e = 400000 / 16;   // 12500 + 25000
    const int nblk = (nsub_n + nsub_e + MLP_WAVES - 1) / MLP_WAVES;  // 4688
    mlp_logits_both<<<nblk, 512, MLP_LDS_BYTES, stream>>>(
        Xn, Xe, W1f_n, W2f_n, W1f_e, W2f_e,
        bn1, bn2, Wn3, bn3, be1, be2, We3, be3,
        log_n, log_e, nsub_n, nsub_e);

    pool_both<<<4096, 256, 0, stream>>>(Xn, Xe, idxn, idxe, log_n, log_e, out);
}

// Round 9
// 832.060 us; speedup vs baseline: 1.9495x; 1.0380x over previous
//
#include <hip/hip_runtime.h>

typedef unsigned short ushort_t;
typedef __attribute__((ext_vector_type(8))) short short8;
typedef __attribute__((ext_vector_type(4))) float f32x4;

__device__ __forceinline__ ushort_t f2bf(float f) {
    union { float f; unsigned int u; } c; c.f = f;
    unsigned int r = c.u + 0x7fffu + ((c.u >> 16) & 1u);  // RNE
    return (ushort_t)(r >> 16);
}

// ---------------------------------------------------------------------------
// Kernel 0: convert W1 (256x128) and W2 (128x64) fp32 -> bf16 in MFMA
// B-fragment order. Fragment (nt,kt): lane l holds W[k][n] for
// n = nt*16 + (l&15), k = kt*32 + (l>>4)*8 + j, j=0..7 (contiguous 16B).
// ---------------------------------------------------------------------------
__global__ __launch_bounds__(256) void build_wfrags(
    const float* __restrict__ W1, const float* __restrict__ W2,
    ushort_t* __restrict__ W1f, ushort_t* __restrict__ W2f)
{
    int tid = blockIdx.x * 256 + threadIdx.x;
    if (tid < 32768) {
        int j = tid & 7, l = (tid >> 3) & 63, fi = tid >> 9; // fi = nt*8+kt
        int nt = fi >> 3, kt = fi & 7;
        int n = nt * 16 + (l & 15);
        int k = kt * 32 + (l >> 4) * 8 + j;
        W1f[tid] = f2bf(W1[k * 128 + n]);
    } else if (tid < 40960) {
        int u = tid - 32768;
        int j = u & 7, l = (u >> 3) & 63, fi = u >> 9;      // fi = nt*4+kt
        int nt = fi >> 2, kt = fi & 3;
        int n = nt * 16 + (l & 15);
        int k = kt * 32 + (l >> 4) * 8 + j;
        W2f[u] = f2bf(W2[k * 64 + n]);
    }
}

// ---------------------------------------------------------------------------
// Kernel 1 (R9): merged MLP, W1 BACK IN LDS + 16-deep X prefetch.
// R8 counters (first attribution!): mlp_logits_both = 252 µs with MfmaUtil
// 7.9% / VALUBusy 15.5% / HBM 15.4% / Occ 43% -> latency-bound at ~23% issue
// utilization; floor ~100 µs. Cause: 64 L2-latency W1f global loads per
// subtile serialized against MFMAs, X loads buried per-kt (R6 moved them
// in-loop for the reg cap), VGPR=52 -> zero in-flight depth.
// Fix: inner loop becomes pure ds_read+MFMA (W1s/W2s in LDS), all 16 X
// dwordx4 issued before any use. Block side made uniform (nodes blocks then
// edges blocks, no straddler) so each block stages only its W1 (64 KB):
// LDS = 64+16+34 KB = 116.7 KB -> 1 block/CU, 2 waves/SIMD. ILP-for-TLP
// trade, R0-proven body. NO launch_bounds min-waves -> no 128-cap -> no
// spills (R5 lesson; verify WRITE_SIZE stays ~2.4 MB, VGPR ~160-200).
// ---------------------------------------------------------------------------
#define MLP_WAVES 8
#define MLP_LDS_BYTES (65536 + 16384 + MLP_WAVES * 16 * 136 * 2)  // 116736

__global__ __launch_bounds__(512) void mlp_logits_both(
    const float* __restrict__ Xn, const float* __restrict__ Xe,
    const ushort_t* __restrict__ W1f_n, const ushort_t* __restrict__ W2f_n,
    const ushort_t* __restrict__ W1f_e, const ushort_t* __restrict__ W2f_e,
    const float* __restrict__ bn1, const float* __restrict__ bn2,
    const float* __restrict__ Wn3, const float* __restrict__ bn3,
    const float* __restrict__ be1, const float* __restrict__ be2,
    const float* __restrict__ We3, const float* __restrict__ be3,
    float* __restrict__ log_n, float* __restrict__ log_e,
    int nsub_n, int nsub_e, int nblk_n)
{
    extern __shared__ __align__(16) char smem[];
    ushort_t* W1s    = (ushort_t*)smem;             // 65536 B (64 frags)
    ushort_t* W2s    = (ushort_t*)(smem + 65536);   // 16384 B (16 frags)
    ushort_t* h1base = (ushort_t*)(smem + 81920);   // 8 waves * 4352 B

    const int t = threadIdx.x;
    const int w = t >> 6, lane = t & 63;
    const int q = lane >> 4, c16 = lane & 15;

    // block-uniform side select (no straddling: nodes blocks, then edges)
    const bool is_e = (int)blockIdx.x >= nblk_n;
    const float*    X      = is_e ? Xe : Xn;
    const ushort_t* W1f    = is_e ? W1f_e : W1f_n;
    const ushort_t* W2f    = is_e ? W2f_e : W2f_n;
    const float*    b1     = is_e ? be1 : bn1;
    const float*    b2     = is_e ? be2 : bn2;
    const float*    W3     = is_e ? We3 : Wn3;
    const float*    b3     = is_e ? be3 : bn3;
    float*          logits = is_e ? log_e : log_n;
    const int       nsub   = is_e ? nsub_e : nsub_n;

    // cooperative stage of this side's W1 (64 KB) + W2 (16 KB); L2-hot
    {
        const f32x4* s1 = (const f32x4*)W1f; f32x4* d1 = (f32x4*)W1s;
        for (int i = t; i < 4096; i += 512) d1[i] = s1[i];
        const f32x4* s2 = (const f32x4*)W2f; f32x4* d2 = (f32x4*)W2s;
        for (int i = t; i < 1024; i += 512) d2[i] = s2[i];
    }
    __syncthreads();

    const int s = (is_e ? (int)blockIdx.x - nblk_n : (int)blockIdx.x) * MLP_WAVES + w;
    if (s >= nsub) return;   // no barriers below: safe exit

    float bias1[8], bias2[4], w3v[4];
    #pragma unroll
    for (int nt = 0; nt < 8; ++nt) bias1[nt] = b1[nt * 16 + c16];
    #pragma unroll
    for (int nt = 0; nt < 4; ++nt) bias2[nt] = b2[nt * 16 + c16];
    #pragma unroll
    for (int nt = 0; nt < 4; ++nt) w3v[nt] = W3[nt * 16 + c16];
    const float b3v = b3[0];

    ushort_t* hw = h1base + w * (16 * 136);   // wave-private scratch

    const float* xp = X + (size_t)(s * 16 + c16) * 256 + q * 8;

    // issue ALL 16 X loads (256 B/lane, HBM) before any use — 16-deep MLP
    f32x4 xv[16];
    #pragma unroll
    for (int kt = 0; kt < 8; ++kt) {
        xv[2 * kt]     = *(const f32x4*)(xp + kt * 32);
        xv[2 * kt + 1] = *(const f32x4*)(xp + kt * 32 + 4);
    }

    // Layer 1: [16x256] @ [256x128] — inner loop is pure LDS + MFMA
    f32x4 acc[8];
    #pragma unroll
    for (int nt = 0; nt < 8; ++nt) acc[nt] = (f32x4){0.f, 0.f, 0.f, 0.f};
    #pragma unroll
    for (int kt = 0; kt < 8; ++kt) {
        short8 a;
        #pragma unroll
        for (int j = 0; j < 4; ++j) {
            a[j]     = (short)f2bf(xv[2 * kt][j]);
            a[4 + j] = (short)f2bf(xv[2 * kt + 1][j]);
        }
        #pragma unroll
        for (int nt = 0; nt < 8; ++nt) {
            short8 bf = *(const short8*)(W1s + ((nt * 8 + kt) * 64 + lane) * 8);
            acc[nt] = __builtin_amdgcn_mfma_f32_16x16x32_bf16(a, bf, acc[nt], 0, 0, 0);
        }
    }

    // bias+relu, C-layout -> row-major bf16 in wave-private LDS
    #pragma unroll
    for (int nt = 0; nt < 8; ++nt)
        #pragma unroll
        for (int reg = 0; reg < 4; ++reg)
            hw[(q * 4 + reg) * 136 + nt * 16 + c16] =
                f2bf(fmaxf(acc[nt][reg] + bias1[nt], 0.f));

    // Layer 2: [16x128] @ [128x64]  (same-wave ds_write->ds_read, no barrier)
    f32x4 acc2[4];
    #pragma unroll
    for (int nt = 0; nt < 4; ++nt) acc2[nt] = (f32x4){0.f, 0.f, 0.f, 0.f};
    #pragma unroll
    for (int kt = 0; kt < 4; ++kt) {
        short8 a = *(const short8*)(hw + c16 * 136 + kt * 32 + q * 8);
        #pragma unroll
        for (int nt = 0; nt < 4; ++nt) {
            short8 bf = *(const short8*)(W2s + ((nt * 4 + kt) * 64 + lane) * 8);
            acc2[nt] = __builtin_amdgcn_mfma_f32_16x16x32_bf16(a, bf, acc2[nt], 0, 0, 0);
        }
    }

    // Layer 3: relu, dot with W3, reduce over 16 lanes per quad
    float p[4];
    #pragma unroll
    for (int reg = 0; reg < 4; ++reg) {
        float v = 0.f;
        #pragma unroll
        for (int nt = 0; nt < 4; ++nt)
            v += fmaxf(acc2[nt][reg] + bias2[nt], 0.f) * w3v[nt];
        p[reg] = v;
    }
    #pragma unroll
    for (int msk = 1; msk < 16; msk <<= 1)
        #pragma unroll
        for (int reg = 0; reg < 4; ++reg)
            p[reg] += __shfl_xor(p[reg], msk);
    if (c16 == 0) {
        #pragma unroll
        for (int reg = 0; reg < 4; ++reg)
            logits[s * 16 + q * 4 + reg] = p[reg] + b3v;
    }
}

// ---------------------------------------------------------------------------
// Kernel 2 (unchanged from R8): merged per-graph softmax + weighted pooling,
// nodes+edges in one 4096-block dispatch (block-uniform select).
// ---------------------------------------------------------------------------
__global__ __launch_bounds__(256) void pool_both(
    const float* __restrict__ Xn, const float* __restrict__ Xe,
    const int* __restrict__ idxn, const int* __restrict__ idxe,
    const float* __restrict__ log_n, const float* __restrict__ log_e,
    float* __restrict__ out)
{
    const int gb = blockIdx.x;
    const bool is_e = (gb >= 2048);
    const int g = is_e ? gb - 2048 : gb;
    const float* X      = is_e ? Xe : Xn;
    const int*   idx    = is_e ? idxe : idxn;
    const float* logits = is_e ? log_e : log_n;
    const int    nrows  = is_e ? 400000 : 200000;

    const int t = threadIdx.x;
    const int w = t >> 6, lane = t & 63;

    int lo = 0, hi = nrows;
    while (lo < hi) { int mid = (lo + hi) >> 1; if (idx[mid] < g) lo = mid + 1; else hi = mid; }
    const int start = lo;
    hi = nrows;
    while (lo < hi) { int mid = (lo + hi) >> 1; if (idx[mid] < g + 1) lo = mid + 1; else hi = mid; }
    const int cnt = lo - start;

    __shared__ float red[8];
    __shared__ float parts[4][256];

    const float* lg = logits + start;

    // segment max
    float m = -3.0e38f;
    for (int i = t; i < cnt; i += 256) m = fmaxf(m, lg[i]);
    #pragma unroll
    for (int o = 32; o; o >>= 1) m = fmaxf(m, __shfl_xor(m, o));
    if (lane == 0) red[w] = m;
    __syncthreads();
    m = fmaxf(fmaxf(red[0], red[1]), fmaxf(red[2], red[3]));

    // segment exp-sum
    float ssum = 0.f;
    for (int i = t; i < cnt; i += 256) ssum += __expf(lg[i] - m);
    #pragma unroll
    for (int o = 32; o; o >>= 1) ssum += __shfl_xor(ssum, o);
    if (lane == 0) red[4 + w] = ssum;
    __syncthreads();
    ssum = red[4] + red[5] + red[6] + red[7];
    const float inv = (cnt > 0) ? 1.f / ssum : 0.f;

    // weighted accumulation: wave w rows {w, w+4, ...}, lane dims lane*4..+3
    f32x4 acc = {0.f, 0.f, 0.f, 0.f};
    const float* xb = X + (size_t)start * 256 + lane * 4;
    int r = w;
    for (; r + 12 < cnt; r += 16) {
        float a0 = __expf(lg[r] - m);
        float a1 = __expf(lg[r + 4] - m);
        float a2 = __expf(lg[r + 8] - m);
        float a3 = __expf(lg[r + 12] - m);
        f32x4 x0 = *(const f32x4*)(xb + (size_t)(r) * 256);
        f32x4 x1 = *(const f32x4*)(xb + (size_t)(r + 4) * 256);
        f32x4 x2 = *(const f32x4*)(xb + (size_t)(r + 8) * 256);
        f32x4 x3 = *(const f32x4*)(xb + (size_t)(r + 12) * 256);
        acc += a0 * x0;
        acc += a1 * x1;
        acc += a2 * x2;
        acc += a3 * x3;
    }
    for (; r < cnt; r += 4) {
        float a = __expf(lg[r] - m);
        f32x4 xv = *(const f32x4*)(xb + (size_t)r * 256);
        acc += a * xv;
    }
    #pragma unroll
    for (int j = 0; j < 4; ++j) parts[w][lane * 4 + j] = acc[j] * inv;
    __syncthreads();
    out[(size_t)gb * 256 + t] = parts[0][t] + parts[1][t] + parts[2][t] + parts[3][t];
}

// ---------------------------------------------------------------------------

extern "C" void kernel_launch(void* const* d_in, const int* in_sizes, int n_in,
                              void* d_out, int out_size, void* d_ws, size_t ws_size,
                              hipStream_t stream) {
    const float* Xn  = (const float*)d_in[0];
    const float* Xe  = (const float*)d_in[1];
    const int* idxn  = (const int*)d_in[2];
    const int* idxe  = (const int*)d_in[3];
    const float* Wn1 = (const float*)d_in[4];
    const float* bn1 = (const float*)d_in[5];
    const float* Wn2 = (const float*)d_in[6];
    const float* bn2 = (const float*)d_in[7];
    const float* Wn3 = (const float*)d_in[8];
    const float* bn3 = (const float*)d_in[9];
    const float* We1 = (const float*)d_in[10];
    const float* be1 = (const float*)d_in[11];
    const float* We2 = (const float*)d_in[12];
    const float* be2 = (const float*)d_in[13];
    const float* We3 = (const float*)d_in[14];
    const float* be3 = (const float*)d_in[15];
    float* out = (float*)d_out;

    char* ws = (char*)d_ws;
    ushort_t* W1f_n = (ushort_t*)(ws + 0);        // 65536 B
    ushort_t* W2f_n = (ushort_t*)(ws + 65536);    // 16384 B
    ushort_t* W1f_e = (ushort_t*)(ws + 81920);    // 65536 B
    ushort_t* W2f_e = (ushort_t*)(ws + 147456);   // 16384 B
    float* log_n = (float*)(ws + 163840);         // 200000*4 B
    float* log_e = (float*)(ws + 963840);         // 400000*4 B

    (void)hipFuncSetAttribute((const void*)mlp_logits_both,
                              hipFuncAttributeMaxDynamicSharedMemorySize,
                              MLP_LDS_BYTES);

    build_wfrags<<<160, 256, 0, stream>>>(Wn1, Wn2, W1f_n, W2f_n);
    build_wfrags<<<160, 256, 0, stream>>>(We1, We2, W1f_e, W2f_e);

    const int nsub_n = 200000 / 16, nsub_e = 400000 / 16;   // 12500 + 25000
    const int nblk_n = (nsub_n + MLP_WAVES - 1) / MLP_WAVES; // 1563
    const int nblk_e = (nsub_e + MLP_WAVES - 1) / MLP_WAVES; // 3125
    mlp_logits_both<<<nblk_n + nblk_e, 512, MLP_LDS_BYTES, stream>>>(
        Xn, Xe, W1f_n, W2f_n, W1f_e, W2f_e,
        bn1, bn2, Wn3, bn3, be1, be2, We3, be3,
        log_n, log_e, nsub_n, nsub_e, nblk_n);

    pool_both<<<4096, 256, 0, stream>>>(Xn, Xe, idxn, idxe, log_n, log_e, out);
}